// Round 3
// baseline (730.163 us; speedup 1.0000x reference)
//
#include <hip/hip_runtime.h>
#include <hip/hip_bf16.h>

typedef __attribute__((ext_vector_type(4))) float f32x4;
typedef __attribute__((ext_vector_type(8))) short s16x8;
typedef __attribute__((ext_vector_type(4))) short s16x4;
typedef unsigned short u16;

#define NEXP 8
#define DD 1024
#define FF 4096
#define NTOK 8192
#define TM 256          // GEMM M/N tile
#define NTMAX 40        // max M-tiles: 32 + 7 padding + slack

// meta layout (int indices into workspace)
#define M_CNT 0
#define M_OFF 8
#define M_CNT2 16
#define M_NT 24
#define M_TE 32        // tile -> expert [128]
#define M_TB 160       // tile -> slot base [128]
#define M_PERM 288     // [8192] slot -> token
#define M_EIDX (288 + 8192)
#define HBUF_OFF_BYTES (1 << 17)

__device__ __forceinline__ u16 f2b(float f) {
    union { float f; unsigned u; } v; v.f = f;
    unsigned r = v.u + 0x7FFF + ((v.u >> 16) & 1);   // RTN-even
    return (u16)(r >> 16);
}

__device__ __forceinline__ void gload16(const u16* g, u16* l) {
    __builtin_amdgcn_global_load_lds(
        (const __attribute__((address_space(1))) void*)g,
        (__attribute__((address_space(3))) void*)l, 16, 0, 0);
}

__global__ void k_zero(int* meta) {
    if (threadIdx.x < 32) meta[threadIdx.x] = 0;
}

__global__ __launch_bounds__(256) void k_router(const float* __restrict__ x,
                                                const float* __restrict__ wr,
                                                const float* __restrict__ br,
                                                int* __restrict__ meta) {
    int wid = threadIdx.x >> 6, lane = threadIdx.x & 63;
    int tok = blockIdx.x * 4 + wid;
    const float* xr = x + (size_t)tok * DD;
    double s = 0.0;
    #pragma unroll
    for (int j = 0; j < 16; ++j) {
        int idx = j * 64 + lane;
        s += (double)xr[idx] * (double)wr[idx];
    }
    #pragma unroll
    for (int off = 32; off > 0; off >>= 1) s += __shfl_down(s, off);
    if (lane == 0) {
        double key = s + (double)br[0];
        int e = ((int)floor(key)) & 7;   // two's-complement & == mod 8 (non-neg)
        meta[M_EIDX + tok] = e;
        atomicAdd(meta + M_CNT + e, 1);
    }
}

__global__ void k_scan(int* meta) {
    if (threadIdx.x == 0) {
        int off = 0, tt = 0;
        for (int e = 0; e < NEXP; ++e) {
            meta[M_OFF + e] = off;
            int c = meta[M_CNT + e];
            int nt = (c + TM - 1) / TM;
            for (int i = 0; i < nt; ++i) {
                meta[M_TE + tt] = e;
                meta[M_TB + tt] = off + i * TM;
                ++tt;
            }
            off += c;
        }
        meta[M_NT] = tt;
    }
}

__global__ __launch_bounds__(256) void k_assign(int* __restrict__ meta) {
    int t = blockIdx.x * 256 + threadIdx.x;
    if (t < NTOK) {
        int e = meta[M_EIDX + t];
        int pos = atomicAdd(meta + M_CNT2 + e, 1);
        meta[M_PERM + meta[M_OFF + e] + pos] = t;
    }
}

// ---------------- converters ----------------

// x fp32 -> bf16 elementwise
__global__ __launch_bounds__(256) void k_cvtx(const float* __restrict__ in, u16* __restrict__ out) {
    size_t i = ((size_t)blockIdx.x * 256 + threadIdx.x) * 8;
    f32x4 a = *(const f32x4*)(in + i);
    f32x4 b = *(const f32x4*)(in + i + 4);
    s16x8 o;
    o[0] = (short)f2b(a[0]); o[1] = (short)f2b(a[1]); o[2] = (short)f2b(a[2]); o[3] = (short)f2b(a[3]);
    o[4] = (short)f2b(b[0]); o[5] = (short)f2b(b[1]); o[6] = (short)f2b(b[2]); o[7] = (short)f2b(b[3]);
    *(s16x8*)(out + i) = o;
}

// per-expert transpose+convert: in[e][R][C] fp32 -> out[e][C][R] bf16
// XOR-swizzled LDS (8-elem slots), 16B global loads and stores.
__global__ __launch_bounds__(256) void k_cvtT(const float* __restrict__ in, u16* __restrict__ out,
                                              int R, int C) {
    __shared__ u16 tl[64 * 64];
    int e = blockIdx.z;
    const float* src = in + (size_t)e * R * C;
    u16* dst = out + (size_t)e * R * C;
    int r0 = blockIdx.y * 64, c0 = blockIdx.x * 64;
    int t = threadIdx.x;
    int tr = t >> 4;            // 0..15
    int tc = (t & 15) * 4;      // 0..60
    #pragma unroll
    for (int i = 0; i < 4; ++i) {
        int r = tr + i * 16;
        f32x4 v = *(const f32x4*)(src + (size_t)(r0 + r) * C + c0 + tc);
        s16x4 w;
        w[0] = (short)f2b(v[0]); w[1] = (short)f2b(v[1]);
        w[2] = (short)f2b(v[2]); w[3] = (short)f2b(v[3]);
        *(s16x4*)&tl[r * 64 + (((tc >> 3) ^ (r & 7)) << 3) + (tc & 7)] = w;
    }
    __syncthreads();
    int cp = t >> 2;            // dst row (= src col) 0..63
    int g = t & 3;
    #pragma unroll
    for (int h = 0; h < 2; ++h) {
        s16x8 w;
        #pragma unroll
        for (int j = 0; j < 8; ++j) {
            int rp = g * 16 + h * 8 + j;
            w[j] = (short)tl[rp * 64 + (((cp >> 3) ^ (rp & 7)) << 3) + (cp & 7)];
        }
        *(s16x8*)(dst + (size_t)(c0 + cp) * R + r0 + g * 16 + h * 8) = w;
    }
}

// ---------------- 256x256 grouped GEMM, 4-deep counted-vmcnt pipeline ----------------
// A: [rows][KDIM] bf16 (PH1: xh via perm; PH2: hbuf grouped).  B: WT[e][NDIM][KDIM] bf16.
// 512 threads = 8 waves (4M x 2N), per-wave 64M x 128N, BK=32, LDS ring of 4 x 32KB.
template <int PH, int KDIM, int NDIM>
__global__ __launch_bounds__(512, 2) void k_gemm3(const u16* __restrict__ Ah,
                                                  const u16* __restrict__ WT,
                                                  const float* __restrict__ bias,
                                                  u16* __restrict__ hout,
                                                  float* __restrict__ fout,
                                                  const int* __restrict__ meta) {
    __shared__ __attribute__((aligned(16))) u16 LB[65536];   // 128 KiB: 4 bufs x (A 8192 + B 8192)

    int total = gridDim.x * gridDim.y;
    int lin = blockIdx.y * gridDim.x + blockIdx.x;
    int q = total >> 3;
    int sw = (lin & 7) * q + (lin >> 3);      // bijective: total % 8 == 0
    int bx = sw % gridDim.x;
    int by = sw / gridDim.x;

    if (bx >= meta[M_NT]) return;
    int e = meta[M_TE + bx];
    int sb = meta[M_TB + bx];
    int send = meta[M_OFF + e] + meta[M_CNT + e];
    const int* perm = meta + M_PERM;
    int nb = by * TM;

    int t = threadIdx.x;
    int lane = t & 63, wid = t >> 6;
    int wm = wid >> 1, wn = wid & 1;
    int lr = lane & 15, lg = lane >> 4;

    // staging sources: 2 A-rows and 2 B-rows per thread; phys slot t&3 holds
    // logical k-slot (t&3)^(row&3)  (row&3 == (t>>2)&3 for both rows)
    int ksrc = (((t & 3) ^ ((t >> 2) & 3))) * 8;
    const u16* sA[2];
    const u16* sB[2];
    #pragma unroll
    for (int i = 0; i < 2; ++i) {
        int row = (t >> 2) + i * 128;
        int s = sb + row; if (s >= send) s = send - 1;
        int tok = (PH == 1) ? perm[s] : s;
        sA[i] = Ah + (size_t)tok * KDIM + ksrc;
        sB[i] = WT + ((size_t)e * NDIM + (nb + row)) * KDIM + ksrc;
    }

    f32x4 acc[4][8];
    #pragma unroll
    for (int i = 0; i < 4; ++i)
        #pragma unroll
        for (int j = 0; j < 8; ++j) acc[i][j] = (f32x4){0.f, 0.f, 0.f, 0.f};

    auto STAGE = [&](int tile) {
        int b = tile & 3;
        int k0 = tile << 5;
        u16* base = &LB[b * 16384];
        gload16(sA[0] + k0, base + t * 8);
        gload16(sA[1] + k0, base + 4096 + t * 8);
        gload16(sB[0] + k0, base + 8192 + t * 8);
        gload16(sB[1] + k0, base + 12288 + t * 8);
    };

    auto COMPUTE = [&](int b) {
        const u16* pA = &LB[b * 16384];
        const u16* pB = pA + 8192;
        int sl = (lg ^ (lr & 3)) * 8;      // phys slot for logical k-slot lg
        s16x8 af[4], bf[8];
        #pragma unroll
        for (int mi = 0; mi < 4; ++mi) {
            int row = wm * 64 + mi * 16 + lr;
            af[mi] = *(const s16x8*)&pA[row * 32 + sl];
        }
        #pragma unroll
        for (int ni = 0; ni < 8; ++ni) {
            int row = wn * 128 + ni * 16 + lr;
            bf[ni] = *(const s16x8*)&pB[row * 32 + sl];
        }
        __builtin_amdgcn_s_setprio(1);
        #pragma unroll
        for (int mi = 0; mi < 4; ++mi)
            #pragma unroll
            for (int ni = 0; ni < 8; ++ni)
                acc[mi][ni] = __builtin_amdgcn_mfma_f32_16x16x32_bf16(af[mi], bf[ni], acc[mi][ni], 0, 0, 0);
        __builtin_amdgcn_s_setprio(0);
    };

    const int NK = KDIM / 32;
    STAGE(0); STAGE(1); STAGE(2);
    #pragma unroll 4
    for (int tt = 0; tt < NK; ++tt) {
        // wait until MY tile-tt loads have landed (3 tiles x 4 loads in flight steady-state)
        if (tt < NK - 2)      asm volatile("s_waitcnt vmcnt(8)" ::: "memory");
        else if (tt == NK - 2) asm volatile("s_waitcnt vmcnt(4)" ::: "memory");
        else                   asm volatile("s_waitcnt vmcnt(0)" ::: "memory");
        __builtin_amdgcn_s_barrier();       // everyone's tile-tt landed; everyone done reading buf[(tt-1)&3]
        asm volatile("" ::: "memory");
        if (tt + 3 < NK) STAGE(tt + 3);     // overwrites buf[(tt-1)&3] — safe after barrier
        COMPUTE(tt & 3);
    }

    // ---- epilogue (C/D map: col=lane&15, row=(lane>>4)*4+reg)
    if constexpr (PH == 1) {
        #pragma unroll
        for (int ni = 0; ni < 8; ++ni) {
            int f = nb + wn * 128 + ni * 16 + lr;
            float bv = bias[(size_t)e * NDIM + f];
            #pragma unroll
            for (int mi = 0; mi < 4; ++mi) {
                int srow = sb + wm * 64 + mi * 16 + lg * 4;
                #pragma unroll
                for (int j = 0; j < 4; ++j) {
                    int sr = srow + j;
                    if (sr < send) {
                        float v = acc[mi][ni][j] + bv;
                        v = v > 0.f ? v : 0.f;
                        hout[(size_t)sr * NDIM + f] = f2b(v);
                    }
                }
            }
        }
    } else {
        #pragma unroll
        for (int ni = 0; ni < 8; ++ni) {
            int d = nb + wn * 128 + ni * 16 + lr;
            float bv = bias[(size_t)e * NDIM + d];
            #pragma unroll
            for (int mi = 0; mi < 4; ++mi) {
                int srow = sb + wm * 64 + mi * 16 + lg * 4;
                #pragma unroll
                for (int j = 0; j < 4; ++j) {
                    int sr = srow + j;
                    if (sr < send) {
                        fout[(size_t)perm[sr] * NDIM + d] = acc[mi][ni][j] + bv;
                    }
                }
            }
        }
    }
}

extern "C" void kernel_launch(void* const* d_in, const int* in_sizes, int n_in,
                              void* d_out, int out_size, void* d_ws, size_t ws_size,
                              hipStream_t stream) {
    const float* x  = (const float*)d_in[0];
    const float* wr = (const float*)d_in[1];
    const float* br = (const float*)d_in[2];
    const float* W1 = (const float*)d_in[3];
    const float* b1 = (const float*)d_in[4];
    const float* W2 = (const float*)d_in[5];
    const float* b2 = (const float*)d_in[6];
    float* out = (float*)d_out;
    int* meta = (int*)d_ws;

    const size_t HB = (size_t)NTOK * FF * 2;       // hbuf bf16 (64 MB)
    const size_t XB = (size_t)NTOK * DD * 2;       // xh bf16 (16 MB)
    u16* hbuf = (u16*)((char*)d_ws + HBUF_OFF_BYTES);
    u16* xh   = (u16*)((char*)d_ws + HBUF_OFF_BYTES + HB);
    u16* wt   = (u16*)((char*)d_ws + HBUF_OFF_BYTES + HB + XB);

    k_zero<<<1, 64, 0, stream>>>(meta);
    k_router<<<NTOK / 4, 256, 0, stream>>>(x, wr, br, meta);
    k_scan<<<1, 64, 0, stream>>>(meta);
    k_assign<<<NTOK / 256, 256, 0, stream>>>(meta);

    k_cvtx<<<(NTOK * DD) / (256 * 8), 256, 0, stream>>>(x, xh);
    k_cvtT<<<dim3(FF / 64, DD / 64, NEXP), 256, 0, stream>>>(W1, wt, DD, FF);
    k_gemm3<1, DD, FF><<<dim3(NTMAX, FF / TM), 512, 0, stream>>>(xh, wt, b1, hbuf, nullptr, meta);
    k_cvtT<<<dim3(DD / 64, FF / 64, NEXP), 256, 0, stream>>>(W2, wt, FF, DD);
    k_gemm3<2, FF, DD><<<dim3(NTMAX, DD / TM), 512, 0, stream>>>(hbuf, wt, b2, nullptr, out, meta);
}